// Round 12
// baseline (293.254 us; speedup 1.0000x reference)
//
#include <hip/hip_runtime.h>
#include <hip/hip_bf16.h>
#include <cstdint>

#define N_TOK 4096
#define DIM   1024
#define HOUT  4096
#define NEXP  8

typedef unsigned short u16;
typedef unsigned int   u32;
typedef __attribute__((ext_vector_type(8))) short short8;
typedef __attribute__((ext_vector_type(4))) float f32x4;

// round-to-nearest-even f32 -> bf16, packed pair into u32 (lo, hi)
__device__ __forceinline__ u32 pack2bf(float lo, float hi){
  u32 a = __float_as_uint(lo);
  a = (a + 0x7fffu + ((a >> 16) & 1u)) >> 16;
  u32 b = __float_as_uint(hi);
  b = (b + 0x7fffu + ((b >> 16) & 1u)) & 0xffff0000u;
  return (a & 0xffffu) | b;
}

// scale two packed bf16 by g, repack via HW cvt_pk (RNE)
__device__ __forceinline__ u32 scale2bf(u32 v, float g){
  float lo = __uint_as_float(v << 16) * g;
  float hi = __uint_as_float(v & 0xffff0000u) * g;
  u32 r;
  asm("v_cvt_pk_bf16_f32 %0, %1, %2" : "=v"(r) : "v"(lo), "v"(hi));
  return r;
}

// async global->LDS, 16B per lane. LDS dest = wave-uniform base + lane*16.
__device__ __forceinline__ void async_copy16(const u16* g, u16* l){
  __builtin_amdgcn_global_load_lds(
      (const __attribute__((address_space(1))) void*)g,
      (__attribute__((address_space(3))) void*)l, 16, 0, 0);
}

__device__ __forceinline__ void wave_barrier(){
  asm volatile("" ::: "memory");
  __builtin_amdgcn_s_barrier();
  asm volatile("" ::: "memory");
}

// ---------------- X f32 -> bf16 (fallback path only) ----------------
__global__ __launch_bounds__(256) void convert_x_kernel(const float* __restrict__ x,
                                                        u32* __restrict__ xb){
  int i = (blockIdx.x * 256 + threadIdx.x) * 8;
  const float4* p = (const float4*)(x + i);
  float4 a = p[0], b = p[1];
  uint4 v;
  v.x = pack2bf(a.x, a.y);
  v.y = pack2bf(a.z, a.w);
  v.z = pack2bf(b.x, b.y);
  v.w = pack2bf(b.z, b.w);
  *(uint4*)(xb + (i >> 1)) = v;
}

// ---- scaled A copies: xs[e][n][d] = bf16(g[n][e] * x[n][d]); x read ONCE ----
__global__ __launch_bounds__(256) void scale_x_kernel(const float* __restrict__ x,
                                                      const float* __restrict__ gates,
                                                      u32* __restrict__ xs){
  int i = blockIdx.x * 256 + threadIdx.x;     // one thread -> 8 elems x 8 experts
  int d8 = (i & 127) * 8;
  int n  = i >> 7;
  const float4* p = (const float4*)(x + (size_t)n * DIM + d8);
  float4 a = p[0], b = p[1];
  const float4* gp = (const float4*)(gates + n * NEXP);
  float4 g0 = gp[0], g1 = gp[1];
  float gv[8] = {g0.x, g0.y, g0.z, g0.w, g1.x, g1.y, g1.z, g1.w};
  #pragma unroll
  for (int e = 0; e < 8; e++){
    float g = gv[e];
    uint4 v;
    v.x = pack2bf(a.x * g, a.y * g);
    v.y = pack2bf(a.z * g, a.w * g);
    v.z = pack2bf(b.x * g, b.y * g);
    v.w = pack2bf(b.z * g, b.w * g);
    *(uint4*)(xs + (((size_t)e * N_TOK + n) * DIM + d8) / 2) = v;
  }
}

// ---------------- W [E][D][H] f32 -> WT [E][H][D] bf16 ----------------
__global__ __launch_bounds__(256) void transpose_w_kernel(const float* __restrict__ W,
                                                          u16* __restrict__ WT){
  __shared__ float tile[64 * 68];
  const int t = threadIdx.x;
  const int h0 = blockIdx.x * 64, d0 = blockIdx.y * 64, e = blockIdx.z;
  const float* Wp = W + (size_t)e * DIM * HOUT + (size_t)d0 * HOUT + h0;
  #pragma unroll
  for (int p = 0; p < 4; p++){
    int d = p * 16 + (t >> 4);
    int c = (t & 15) * 4;
    float4 v = *(const float4*)(Wp + (size_t)d * HOUT + c);
    *(float4*)&tile[d * 68 + c] = v;
  }
  __syncthreads();
  const int h = t >> 2, dc = (t & 3) * 16;
  u32 o[8];
  #pragma unroll
  for (int j = 0; j < 8; j++){
    float v0 = tile[(dc + 2 * j)     * 68 + h];
    float v1 = tile[(dc + 2 * j + 1) * 68 + h];
    o[j] = pack2bf(v0, v1);
  }
  u16* dst = WT + (size_t)e * HOUT * DIM + (size_t)(h0 + h) * DIM + d0 + dc;
  uint4 v0; v0.x = o[0]; v0.y = o[1]; v0.z = o[2]; v0.w = o[3];
  uint4 v1; v1.x = o[4]; v1.y = o[5]; v1.z = o[6]; v1.w = o[7];
  *(uint4*)(dst)     = v0;
  *(uint4*)(dst + 8) = v1;
}

// ---------------- noisy top-4 gating (f32, one wave per token) ----------------
__global__ __launch_bounds__(256) void gating_kernel(const float* __restrict__ x,
                                                     const float* __restrict__ noise,
                                                     const float* __restrict__ w_gate,
                                                     const float* __restrict__ w_noise,
                                                     float* __restrict__ gates){
  const int lane = threadIdx.x & 63;
  const int n = blockIdx.x * 4 + (threadIdx.x >> 6);
  float ag[8], an[8];
  #pragma unroll
  for (int e = 0; e < 8; e++){ ag[e] = 0.f; an[e] = 0.f; }
  const float* xr = x + (size_t)n * DIM;
  for (int i = 0; i < DIM / 64; i++){
    int d = i * 64 + lane;
    float xv = xr[d];
    float4 g0 = *(const float4*)(w_gate  + d * 8);
    float4 g1 = *(const float4*)(w_gate  + d * 8 + 4);
    float4 s0 = *(const float4*)(w_noise + d * 8);
    float4 s1 = *(const float4*)(w_noise + d * 8 + 4);
    ag[0] += xv * g0.x; ag[1] += xv * g0.y; ag[2] += xv * g0.z; ag[3] += xv * g0.w;
    ag[4] += xv * g1.x; ag[5] += xv * g1.y; ag[6] += xv * g1.z; ag[7] += xv * g1.w;
    an[0] += xv * s0.x; an[1] += xv * s0.y; an[2] += xv * s0.z; an[3] += xv * s0.w;
    an[4] += xv * s1.x; an[5] += xv * s1.y; an[6] += xv * s1.z; an[7] += xv * s1.w;
  }
  #pragma unroll
  for (int off = 32; off > 0; off >>= 1){
    #pragma unroll
    for (int e = 0; e < 8; e++){
      ag[e] += __shfl_xor(ag[e], off);
      an[e] += __shfl_xor(an[e], off);
    }
  }
  if (lane == 0){
    float lg[8];
    #pragma unroll
    for (int e = 0; e < 8; e++){
      float z = an[e];
      float sp = fmaxf(z, 0.f) + log1pf(expf(-fabsf(z)));
      lg[e] = ag[e] + noise[n * 8 + e] * (sp + 1e-2f);
    }
    bool used[8] = {false,false,false,false,false,false,false,false};
    float tv[4]; int ti[4];
    #pragma unroll
    for (int k = 0; k < 4; k++){
      float best = -1e30f; int bi = 0;
      #pragma unroll
      for (int e = 0; e < 8; e++)
        if (!used[e] && lg[e] > best){ best = lg[e]; bi = e; }
      used[bi] = true; tv[k] = best; ti[k] = bi;
    }
    float m = tv[0];
    float w[4]; float s = 0.f;
    #pragma unroll
    for (int k = 0; k < 4; k++){ w[k] = expf(tv[k] - m); s += w[k]; }
    float inv = 1.f / s;
    float res[8] = {0.f,0.f,0.f,0.f,0.f,0.f,0.f,0.f};
    #pragma unroll
    for (int k = 0; k < 4; k++) res[ti[k]] = w[k] * inv;
    float4* gp = (float4*)(gates + n * 8);
    float4 r0; r0.x = res[0]; r0.y = res[1]; r0.z = res[2]; r0.w = res[3];
    float4 r1; r1.x = res[4]; r1.y = res[5]; r1.z = res[6]; r1.w = res[7];
    gp[0] = r0; gp[1] = r1;
  }
}

// ============ 256x256 8-phase GEMM over pre-scaled A (xs) ============
// Counted-vmcnt ledger (2 loads per half-tile), steady state:
//   end P1: vmcnt(6) completes B1(u)   [read P2 after barrier]
//   end P2: vmcnt(6) completes A1(u)   [read P3 after barrier]
//   end P3: no wait
//   end P4: vmcnt(6) completes A0(u+1), B0(u+1)  [read P1(u+1) after barrier]
// Certification invariant: own-wave vmcnt BEFORE a barrier; cross-wave-staged
// data only ds_read AFTER that barrier.
__global__ __launch_bounds__(512, 1) void moe_gemm_8ph_kernel(
    const u16* __restrict__ xs, const u16* __restrict__ wt,
    const float* __restrict__ gates, const float* __restrict__ bias,
    float* __restrict__ out){
  __shared__ u16 ldsA[2][16384];   // [buf][256 rows x 64 k] 32 KB each
  __shared__ u16 ldsB[2][16384];
  const int t    = threadIdx.x;
  const int lane = t & 63;
  const int wave = t >> 6;
  const int wm = wave >> 2;              // 0..1
  const int wn = wave & 3;               // 0..3
  const int l15 = lane & 15, lgp = lane >> 4;
  const int l7 = lane & 7, l8 = lane >> 3;

  // bijective XCD swizzle: 256 wgs = 8 XCDs x 32
  const int wg = (blockIdx.x & 7) * 32 + (blockIdx.x >> 3);
  const int t0 = (wg & 15) * 256, h0 = (wg >> 4) * 256;

  const f32x4 z4 = {0.f, 0.f, 0.f, 0.f};
  f32x4 acc[8][4];
  #pragma unroll
  for (int m = 0; m < 8; m++)
    #pragma unroll
    for (int n = 0; n < 4; n++) acc[m][n] = z4;

  // swizzled read chunk offsets (u16 units): chunk = (ks*4+lgp) ^ (l15&7)
  const int co[2] = { ((0 + lgp) ^ (l15 & 7)) << 3, ((4 + lgp) ^ (l15 & 7)) << 3 };

  // staging: lane l covers row w*16 + i*8 + (l>>3); physical chunk l&7 holds
  // logical (l&7)^(l>>3) (pre-swizzled global source, linear LDS dest).
  const int srcChunkOff = ((l7 ^ l8) << 3);            // u16
  const int srcRowOff   = (l8) << 10;                  // row (l>>3) * 1024 elems
  const int ldsLaneOff  = lane << 3;                   // lane * 16B

  #define STAGE_HALF(srcbase, ldshalf)                                            \
    {                                                                             \
      const u16* _g = (srcbase) + ((size_t)(wave * 16) << 10) + srcRowOff + srcChunkOff; \
      u16* _l = (ldshalf) + (wave << 10) + ldsLaneOff;                            \
      async_copy16(_g, _l);                                                       \
      async_copy16(_g + (8 << 10), _l + 512);                                     \
    }

  #define SRC_A(s, H) (xs + (((size_t)((s) >> 4) * N_TOK + t0 + (H) * 128) << 10) + (((s) & 15) << 6))
  #define SRC_B(s, H) (wt + (((size_t)((s) >> 4) * HOUT + h0 + (H) * 128) << 10) + (((s) & 15) << 6))

  short8 af[4][2], bf[2][2];

  #define LOAD_A(mh)                                                              \
    _Pragma("unroll") for (int m2 = 0; m2 < 4; m2++)                              \
      _Pragma("unroll") for (int ks = 0; ks < 2; ks++)                            \
        af[m2][ks] = *(const short8*)(&ldsA[p][(((mh) * 128 + wm * 64 + m2 * 16 + l15) << 6) + co[ks]]);

  #define LOAD_B(nh)                                                              \
    _Pragma("unroll") for (int n2 = 0; n2 < 2; n2++)                              \
      _Pragma("unroll") for (int ks = 0; ks < 2; ks++)                            \
        bf[n2][ks] = *(const short8*)(&ldsB[p][((wn * 64 + (nh) * 32 + n2 * 16 + l15) << 6) + co[ks]]);

  #define MFMA_Q(mh, nh)                                                          \
    __builtin_amdgcn_s_setprio(1);                                                \
    _Pragma("unroll") for (int m2 = 0; m2 < 4; m2++)                              \
      _Pragma("unroll") for (int n2 = 0; n2 < 2; n2++)                            \
        _Pragma("unroll") for (int ks = 0; ks < 2; ks++)                          \
          acc[(mh) * 4 + m2][(nh) * 2 + n2] = __builtin_amdgcn_mfma_f32_16x16x32_bf16( \
              af[m2][ks], bf[n2][ks], acc[(mh) * 4 + m2][(nh) * 2 + n2], 0, 0, 0); \
    __builtin_amdgcn_s_setprio(0);

  #define WAIT6 asm volatile("s_waitcnt vmcnt(6)" ::: "memory")
  #define WAIT0 asm volatile("s_waitcnt vmcnt(0)" ::: "memory")

  const int NT = NEXP * 16;   // 128 K-tiles

  // prologue in ledger order: A0(0), B0(0), B1(0), A1(0), A0(1)
  STAGE_HALF(SRC_A(0, 0), &ldsA[0][0]);
  STAGE_HALF(SRC_B(0, 0), &ldsB[0][0]);
  STAGE_HALF(SRC_B(0, 1), &ldsB[0][8192]);
  STAGE_HALF(SRC_A(0, 1), &ldsA[0][8192]);
  STAGE_HALF(SRC_A(1, 0), &ldsA[1][0]);
  WAIT6;                      // completes A0(0), B0(0)
  wave_barrier();

  for (int u = 0; u < NT; ++u){
    const int p = u & 1;
    const int s1 = u + 1, s2 = u + 2;
    const bool deep = (u < NT - 2);
    // ---- P1: Q(0,0) ---- stage B0(s1)
    LOAD_A(0); LOAD_B(0);
    if (s1 < NT) STAGE_HALF(SRC_B(s1, 0), &ldsB[p ^ 1][0]);
    MFMA_Q(0, 0);
    if (deep) { WAIT6; } else { WAIT0; }
    wave_barrier();
    // ---- P2: Q(0,1) ---- stage B1(s1)
    LOAD_B(1);
    if (s1 < NT) STAGE_HALF(SRC_B(s1, 1), &ldsB[p ^ 1][8192]);
    MFMA_Q(0, 1);
    if (deep) { WAIT6; } else { WAIT0; }
    wave_barrier();
    // ---- P3: Q(1,1) ---- stage A1(s1), no wait
    LOAD_A(1);
    if (s1 < NT) STAGE_HALF(SRC_A(s1, 1), &ldsA[p ^ 1][8192]);
    MFMA_Q(1, 1);
    wave_barrier();
    // ---- P4: Q(1,0) ---- stage A0(s2) into buf[p] (half0 last read in P1)
    LOAD_B(0);
    if (s2 < NT) STAGE_HALF(SRC_A(s2, 0), &ldsA[p][0]);
    MFMA_Q(1, 0);
    if (deep) { WAIT6; } else { WAIT0; }
    wave_barrier();
  }

  // epilogue: C frag layout col=l15, row=lgp*4+rr
  float bv[8][4];
  #pragma unroll
  for (int e = 0; e < 8; e++)
    #pragma unroll
    for (int n = 0; n < 4; n++)
      bv[e][n] = bias[e * HOUT + h0 + wn * 64 + n * 16 + l15];
  #pragma unroll
  for (int m = 0; m < 8; m++){
    const int mh = m >> 2, m2 = m & 3;
    #pragma unroll
    for (int rr = 0; rr < 4; rr++){
      const int tok = t0 + mh * 128 + wm * 64 + m2 * 16 + lgp * 4 + rr;
      const float4* gp = (const float4*)(gates + tok * NEXP);
      float4 g0 = gp[0], g1 = gp[1];
      #pragma unroll
      for (int n = 0; n < 4; n++){
        float gb = g0.x * bv[0][n] + g0.y * bv[1][n] + g0.z * bv[2][n] + g0.w * bv[3][n]
                 + g1.x * bv[4][n] + g1.y * bv[5][n] + g1.z * bv[6][n] + g1.w * bv[7][n];
        out[(size_t)tok * HOUT + h0 + wn * 64 + n * 16 + l15] = acc[m][n][rr] + gb;
      }
    }
  }
  #undef STAGE_HALF
  #undef SRC_A
  #undef SRC_B
  #undef LOAD_A
  #undef LOAD_B
  #undef MFMA_Q
  #undef WAIT6
  #undef WAIT0
}

// ---------------- fallback: round-3 fused GEMM (gate folded at stage) ----------------
__global__ __launch_bounds__(256, 2) void moe_gemm_kernel(
    const u16* __restrict__ xb, const u16* __restrict__ wt,
    const float* __restrict__ gates, const float* __restrict__ bias,
    float* __restrict__ out){
  __shared__ u16 lds_a[2][128 * 64];
  __shared__ u16 lds_b[2][128 * 64];
  const int t    = threadIdx.x;
  const int lane = t & 63;
  const int wave = t >> 6;
  const int wm = wave >> 1, wn = wave & 1;
  const int wg = (blockIdx.x & 7) * 128 + (blockIdx.x >> 3);
  const int t0 = (wg & 31) * 128, h0 = (wg >> 5) * 128;
  const int l15 = lane & 15, lgp = lane >> 4;

  const f32x4 z4 = {0.f, 0.f, 0.f, 0.f};
  f32x4 acc[4][4];
  #pragma unroll
  for (int mi = 0; mi < 4; mi++)
    #pragma unroll
    for (int nj = 0; nj < 4; nj++) acc[mi][nj] = z4;

  int ldsoff[4], srcoff[4], rowid[4];
  #pragma unroll
  for (int j = 0; j < 4; j++){
    int slot = j * 256 + t;
    int r = slot >> 3, c = slot & 7;
    ldsoff[j] = r * 64 + ((c ^ (r & 7)) * 8);
    srcoff[j] = r * DIM + c * 8;
    rowid[j]  = r;
  }
  const u16* aB = xb + (size_t)t0 * DIM;

  float gj[4];
  #pragma unroll
  for (int j = 0; j < 4; j++) gj[j] = gates[(t0 + rowid[j]) * NEXP + 0];

  uint4 ra[4], rb[4];
  {
    const u16* bB = wt + (size_t)h0 * DIM;
    #pragma unroll
    for (int j = 0; j < 4; j++){
      ra[j] = *(const uint4*)(aB + srcoff[j]);
      rb[j] = *(const uint4*)(bB + srcoff[j]);
    }
  }
  #pragma unroll
  for (int j = 0; j < 4; j++){
    uint4 sa;
    sa.x = scale2bf(ra[j].x, gj[j]); sa.y = scale2bf(ra[j].y, gj[j]);
    sa.z = scale2bf(ra[j].z, gj[j]); sa.w = scale2bf(ra[j].w, gj[j]);
    *(uint4*)(&lds_a[0][ldsoff[j]]) = sa;
    *(uint4*)(&lds_b[0][ldsoff[j]]) = rb[j];
  }
  __syncthreads();

  const int NT = NEXP * 16;
  int cur = 0;
  for (int tt = 0; tt < NT; ++tt){
    const int nt_ = tt + 1;
    const bool havenext = nt_ < NT;
    if (havenext){
      const int e = nt_ >> 4, s = nt_ & 15;
      const int k0 = s * 64;
      const u16* aP = aB + k0;
      const u16* bB = wt + ((size_t)e * HOUT + h0) * DIM + k0;
      #pragma unroll
      for (int j = 0; j < 4; j++){
        ra[j] = *(const uint4*)(aP + srcoff[j]);
        rb[j] = *(const uint4*)(bB + srcoff[j]);
      }
      if ((nt_ & 15) == 0){
        #pragma unroll
        for (int j = 0; j < 4; j++) gj[j] = gates[(t0 + rowid[j]) * NEXP + e];
      }
    }
    #pragma unroll
    for (int ks = 0; ks < 2; ks++){
      short8 af[4], bf[4];
      #pragma unroll
      for (int mi = 0; mi < 4; mi++){
        int r = wm * 64 + mi * 16 + l15;
        int ch = (ks * 4 + lgp) ^ (r & 7);
        af[mi] = *(const short8*)(&lds_a[cur][r * 64 + ch * 8]);
      }
      #pragma unroll
      for (int nj = 0; nj < 4; nj++){
        int r = wn * 64 + nj * 16 + l15;
        int ch = (ks * 4 + lgp) ^ (r & 7);
        bf[nj] = *(const short8*)(&lds_b[cur][r * 64 + ch * 8]);
      }
      #pragma unroll
      for (int mi = 0; mi < 4; mi++)
        #pragma unroll
        for (int nj = 0; nj < 4; nj++)
          acc[mi][nj] = __builtin_amdgcn_mfma_f32_16x16x32_bf16(
              af[mi], bf[nj], acc[mi][nj], 0, 0, 0);
    }
    if (havenext){
      #pragma unroll
      for (int j = 0; j < 4; j++){
        uint4 sa;
        sa.x = scale2bf(ra[j].x, gj[j]); sa.y = scale2bf(ra[j].y, gj[j]);
        sa.z = scale2bf(ra[j].z, gj[j]); sa.w = scale2bf(ra[j].w, gj[j]);
        *(uint4*)(&lds_a[cur ^ 1][ldsoff[j]]) = sa;
        *(uint4*)(&lds_b[cur ^ 1][ldsoff[j]]) = rb[j];
      }
    }
    __syncthreads();
    cur ^= 1;
  }

  float bv[8][4];
  #pragma unroll
  for (int e = 0; e < 8; e++)
    #pragma unroll
    for (int nj = 0; nj < 4; nj++)
      bv[e][nj] = bias[e * HOUT + h0 + wn * 64 + nj * 16 + l15];
  #pragma unroll
  for (int mi = 0; mi < 4; mi++)
    #pragma unroll
    for (int r = 0; r < 4; r++){
      const int tok = t0 + wm * 64 + mi * 16 + lgp * 4 + r;
      const float4* gp = (const float4*)(gates + tok * NEXP);
      float4 g0 = gp[0], g1 = gp[1];
      #pragma unroll
      for (int nj = 0; nj < 4; nj++){
        float gb = g0.x * bv[0][nj] + g0.y * bv[1][nj] + g0.z * bv[2][nj] + g0.w * bv[3][nj]
                 + g1.x * bv[4][nj] + g1.y * bv[5][nj] + g1.z * bv[6][nj] + g1.w * bv[7][nj];
        out[(size_t)tok * HOUT + h0 + wn * 64 + nj * 16 + l15] = acc[mi][nj][r] + gb;
      }
    }
}

extern "C" void kernel_launch(void* const* d_in, const int* in_sizes, int n_in,
                              void* d_out, int out_size, void* d_ws, size_t ws_size,
                              hipStream_t stream){
  (void)in_sizes; (void)n_in; (void)out_size;
  const float* x       = (const float*)d_in[0];
  const float* noise   = (const float*)d_in[1];
  const float* w_gate  = (const float*)d_in[2];
  const float* w_noise = (const float*)d_in[3];
  const float* W       = (const float*)d_in[4];
  const float* b       = (const float*)d_in[5];
  float* out = (float*)d_out;

  char* ws = (char*)d_ws;
  const size_t GATES_B = (size_t)N_TOK * NEXP * 4;             // 128 KB
  const size_t XS_B    = (size_t)NEXP * N_TOK * DIM * 2;       // 64 MB (scaled A copies)
  const size_t WT_B    = (size_t)NEXP * HOUT * DIM * 2;        // 64 MB
  const size_t XB_B    = (size_t)N_TOK * DIM * 2;              // 8 MB (fallback)

  if (ws_size >= GATES_B + XS_B + WT_B){
    // ---- primary path: pre-scaled A + 256^2 8-phase GEMM (proven 244.7us) ----
    float* gates = (float*)ws;
    u32*   xs    = (u32*)(ws + GATES_B);
    u16*   wt    = (u16*)(ws + GATES_B + XS_B);
    hipLaunchKernelGGL(gating_kernel, dim3(N_TOK / 4), dim3(256), 0, stream,
                       x, noise, w_gate, w_noise, gates);
    hipLaunchKernelGGL(transpose_w_kernel, dim3(HOUT / 64, DIM / 64, NEXP), dim3(256), 0, stream, W, wt);
    hipLaunchKernelGGL(scale_x_kernel, dim3((N_TOK * DIM / 8) / 256), dim3(256), 0, stream,
                       x, gates, xs);
    hipLaunchKernelGGL(moe_gemm_8ph_kernel, dim3((N_TOK / 256) * (HOUT / 256)), dim3(512), 0, stream,
                       (const u16*)xs, wt, gates, b, out);
  } else if (ws_size >= GATES_B + XB_B + WT_B){
    // ---- fallback: round-3 path ----
    float* gates = (float*)ws;
    u32*   xb    = (u32*)(ws + GATES_B);
    u16*   wt    = (u16*)(ws + GATES_B + XB_B);
    hipLaunchKernelGGL(convert_x_kernel, dim3((N_TOK * DIM) / (256 * 8)), dim3(256), 0, stream, x, xb);
    hipLaunchKernelGGL(transpose_w_kernel, dim3(HOUT / 64, DIM / 64, NEXP), dim3(256), 0, stream, W, wt);
    hipLaunchKernelGGL(gating_kernel, dim3(N_TOK / 4), dim3(256), 0, stream, x, noise, w_gate, w_noise, gates);
    hipLaunchKernelGGL(moe_gemm_kernel, dim3((N_TOK / 128) * (HOUT / 128)), dim3(256), 0, stream,
                       (const u16*)xb, wt, gates, b, out);
  }
}

// Round 13
// 286.473 us; speedup vs baseline: 1.0237x; 1.0237x over previous
//
#include <hip/hip_runtime.h>
#include <hip/hip_bf16.h>
#include <cstdint>

#define N_TOK 4096
#define DIM   1024
#define HOUT  4096
#define NEXP  8

typedef unsigned short u16;
typedef unsigned int   u32;
typedef __attribute__((ext_vector_type(8))) short short8;
typedef __attribute__((ext_vector_type(4))) float f32x4;

// round-to-nearest-even f32 -> bf16, packed pair into u32 (lo, hi)
__device__ __forceinline__ u32 pack2bf(float lo, float hi){
  u32 a = __float_as_uint(lo);
  a = (a + 0x7fffu + ((a >> 16) & 1u)) >> 16;
  u32 b = __float_as_uint(hi);
  b = (b + 0x7fffu + ((b >> 16) & 1u)) & 0xffff0000u;
  return (a & 0xffffu) | b;
}

// scale two packed bf16 by g, repack via HW cvt_pk (RNE)
__device__ __forceinline__ u32 scale2bf(u32 v, float g){
  float lo = __uint_as_float(v << 16) * g;
  float hi = __uint_as_float(v & 0xffff0000u) * g;
  u32 r;
  asm("v_cvt_pk_bf16_f32 %0, %1, %2" : "=v"(r) : "v"(lo), "v"(hi));
  return r;
}

// async global->LDS, 16B per lane. LDS dest = wave-uniform base + lane*16.
__device__ __forceinline__ void async_copy16(const u16* g, u16* l){
  __builtin_amdgcn_global_load_lds(
      (const __attribute__((address_space(1))) void*)g,
      (__attribute__((address_space(3))) void*)l, 16, 0, 0);
}

__device__ __forceinline__ void wave_barrier(){
  asm volatile("" ::: "memory");
  __builtin_amdgcn_s_barrier();
  asm volatile("" ::: "memory");
}

// ---------------- X f32 -> bf16 (fallback path only) ----------------
__global__ __launch_bounds__(256) void convert_x_kernel(const float* __restrict__ x,
                                                        u32* __restrict__ xb){
  int i = (blockIdx.x * 256 + threadIdx.x) * 8;
  const float4* p = (const float4*)(x + i);
  float4 a = p[0], b = p[1];
  uint4 v;
  v.x = pack2bf(a.x, a.y);
  v.y = pack2bf(a.z, a.w);
  v.z = pack2bf(b.x, b.y);
  v.w = pack2bf(b.z, b.w);
  *(uint4*)(xb + (i >> 1)) = v;
}

// ---- scaled A copies: xs[e][n][d] = bf16(g[n][e] * x[n][d]); x read ONCE ----
__global__ __launch_bounds__(256) void scale_x_kernel(const float* __restrict__ x,
                                                      const float* __restrict__ gates,
                                                      u32* __restrict__ xs){
  int i = blockIdx.x * 256 + threadIdx.x;     // one thread -> 8 elems x 8 experts
  int d8 = (i & 127) * 8;
  int n  = i >> 7;
  const float4* p = (const float4*)(x + (size_t)n * DIM + d8);
  float4 a = p[0], b = p[1];
  const float4* gp = (const float4*)(gates + n * NEXP);
  float4 g0 = gp[0], g1 = gp[1];
  float gv[8] = {g0.x, g0.y, g0.z, g0.w, g1.x, g1.y, g1.z, g1.w};
  #pragma unroll
  for (int e = 0; e < 8; e++){
    float g = gv[e];
    uint4 v;
    v.x = pack2bf(a.x * g, a.y * g);
    v.y = pack2bf(a.z * g, a.w * g);
    v.z = pack2bf(b.x * g, b.y * g);
    v.w = pack2bf(b.z * g, b.w * g);
    *(uint4*)(xs + (((size_t)e * N_TOK + n) * DIM + d8) / 2) = v;
  }
}

// ---------------- W [E][D][H] f32 -> WT [E][H][D] bf16 ----------------
__global__ __launch_bounds__(256) void transpose_w_kernel(const float* __restrict__ W,
                                                          u16* __restrict__ WT){
  __shared__ float tile[64 * 68];
  const int t = threadIdx.x;
  const int h0 = blockIdx.x * 64, d0 = blockIdx.y * 64, e = blockIdx.z;
  const float* Wp = W + (size_t)e * DIM * HOUT + (size_t)d0 * HOUT + h0;
  #pragma unroll
  for (int p = 0; p < 4; p++){
    int d = p * 16 + (t >> 4);
    int c = (t & 15) * 4;
    float4 v = *(const float4*)(Wp + (size_t)d * HOUT + c);
    *(float4*)&tile[d * 68 + c] = v;
  }
  __syncthreads();
  const int h = t >> 2, dc = (t & 3) * 16;
  u32 o[8];
  #pragma unroll
  for (int j = 0; j < 8; j++){
    float v0 = tile[(dc + 2 * j)     * 68 + h];
    float v1 = tile[(dc + 2 * j + 1) * 68 + h];
    o[j] = pack2bf(v0, v1);
  }
  u16* dst = WT + (size_t)e * HOUT * DIM + (size_t)(h0 + h) * DIM + d0 + dc;
  uint4 v0; v0.x = o[0]; v0.y = o[1]; v0.z = o[2]; v0.w = o[3];
  uint4 v1; v1.x = o[4]; v1.y = o[5]; v1.z = o[6]; v1.w = o[7];
  *(uint4*)(dst)     = v0;
  *(uint4*)(dst + 8) = v1;
}

// ---------------- noisy top-4 gating (f32, one wave per token) ----------------
__global__ __launch_bounds__(256) void gating_kernel(const float* __restrict__ x,
                                                     const float* __restrict__ noise,
                                                     const float* __restrict__ w_gate,
                                                     const float* __restrict__ w_noise,
                                                     float* __restrict__ gates){
  const int lane = threadIdx.x & 63;
  const int n = blockIdx.x * 4 + (threadIdx.x >> 6);
  float ag[8], an[8];
  #pragma unroll
  for (int e = 0; e < 8; e++){ ag[e] = 0.f; an[e] = 0.f; }
  const float* xr = x + (size_t)n * DIM;
  for (int i = 0; i < DIM / 64; i++){
    int d = i * 64 + lane;
    float xv = xr[d];
    float4 g0 = *(const float4*)(w_gate  + d * 8);
    float4 g1 = *(const float4*)(w_gate  + d * 8 + 4);
    float4 s0 = *(const float4*)(w_noise + d * 8);
    float4 s1 = *(const float4*)(w_noise + d * 8 + 4);
    ag[0] += xv * g0.x; ag[1] += xv * g0.y; ag[2] += xv * g0.z; ag[3] += xv * g0.w;
    ag[4] += xv * g1.x; ag[5] += xv * g1.y; ag[6] += xv * g1.z; ag[7] += xv * g1.w;
    an[0] += xv * s0.x; an[1] += xv * s0.y; an[2] += xv * s0.z; an[3] += xv * s0.w;
    an[4] += xv * s1.x; an[5] += xv * s1.y; an[6] += xv * s1.z; an[7] += xv * s1.w;
  }
  #pragma unroll
  for (int off = 32; off > 0; off >>= 1){
    #pragma unroll
    for (int e = 0; e < 8; e++){
      ag[e] += __shfl_xor(ag[e], off);
      an[e] += __shfl_xor(an[e], off);
    }
  }
  if (lane == 0){
    float lg[8];
    #pragma unroll
    for (int e = 0; e < 8; e++){
      float z = an[e];
      float sp = fmaxf(z, 0.f) + log1pf(expf(-fabsf(z)));
      lg[e] = ag[e] + noise[n * 8 + e] * (sp + 1e-2f);
    }
    bool used[8] = {false,false,false,false,false,false,false,false};
    float tv[4]; int ti[4];
    #pragma unroll
    for (int k = 0; k < 4; k++){
      float best = -1e30f; int bi = 0;
      #pragma unroll
      for (int e = 0; e < 8; e++)
        if (!used[e] && lg[e] > best){ best = lg[e]; bi = e; }
      used[bi] = true; tv[k] = best; ti[k] = bi;
    }
    float m = tv[0];
    float w[4]; float s = 0.f;
    #pragma unroll
    for (int k = 0; k < 4; k++){ w[k] = expf(tv[k] - m); s += w[k]; }
    float inv = 1.f / s;
    float res[8] = {0.f,0.f,0.f,0.f,0.f,0.f,0.f,0.f};
    #pragma unroll
    for (int k = 0; k < 4; k++) res[ti[k]] = w[k] * inv;
    float4* gp = (float4*)(gates + n * 8);
    float4 r0; r0.x = res[0]; r0.y = res[1]; r0.z = res[2]; r0.w = res[3];
    float4 r1; r1.x = res[4]; r1.y = res[5]; r1.z = res[6]; r1.w = res[7];
    gp[0] = r0; gp[1] = r1;
  }
}

// ============ 256x256 8-phase GEMM over pre-scaled A (xs) ============
// Round-5 proven schedule, unchanged sync structure. ONE delta vs round 12:
// B0 kept in persistent b0f registers across the K-tile (P1 read, P4 reuse)
// -> P4's 4 ds_read_b128 re-read deleted (28 -> 24 reads/K-tile/wave).
// Register-liveness change only; MFMA inputs/order identical.
// Counted-vmcnt ledger (2 loads per half-tile), steady state:
//   end P1: vmcnt(6) completes B1(u)   [read P2 after barrier]
//   end P2: vmcnt(6) completes A1(u)   [read P3 after barrier]
//   end P3: no wait
//   end P4: vmcnt(6) completes A0(u+1), B0(u+1)  [read P1(u+1) after barrier]
__global__ __launch_bounds__(512, 1) void moe_gemm_8ph_kernel(
    const u16* __restrict__ xs, const u16* __restrict__ wt,
    const float* __restrict__ gates, const float* __restrict__ bias,
    float* __restrict__ out){
  __shared__ u16 ldsA[2][16384];   // [buf][256 rows x 64 k] 32 KB each
  __shared__ u16 ldsB[2][16384];
  const int t    = threadIdx.x;
  const int lane = t & 63;
  const int wave = t >> 6;
  const int wm = wave >> 2;              // 0..1
  const int wn = wave & 3;               // 0..3
  const int l15 = lane & 15, lgp = lane >> 4;
  const int l7 = lane & 7, l8 = lane >> 3;

  // bijective XCD swizzle: 256 wgs = 8 XCDs x 32
  const int wg = (blockIdx.x & 7) * 32 + (blockIdx.x >> 3);
  const int t0 = (wg & 15) * 256, h0 = (wg >> 4) * 256;

  const f32x4 z4 = {0.f, 0.f, 0.f, 0.f};
  f32x4 acc[8][4];
  #pragma unroll
  for (int m = 0; m < 8; m++)
    #pragma unroll
    for (int n = 0; n < 4; n++) acc[m][n] = z4;

  // swizzled read chunk offsets (u16 units): chunk = (ks*4+lgp) ^ (l15&7)
  const int co[2] = { ((0 + lgp) ^ (l15 & 7)) << 3, ((4 + lgp) ^ (l15 & 7)) << 3 };

  // staging: lane l covers row w*16 + i*8 + (l>>3); physical chunk l&7 holds
  // logical (l&7)^(l>>3) (pre-swizzled global source, linear LDS dest).
  const int srcChunkOff = ((l7 ^ l8) << 3);            // u16
  const int srcRowOff   = (l8) << 10;                  // row (l>>3) * 1024 elems
  const int ldsLaneOff  = lane << 3;                   // lane * 16B

  #define STAGE_HALF(srcbase, ldshalf)                                            \
    {                                                                             \
      const u16* _g = (srcbase) + ((size_t)(wave * 16) << 10) + srcRowOff + srcChunkOff; \
      u16* _l = (ldshalf) + (wave << 10) + ldsLaneOff;                            \
      async_copy16(_g, _l);                                                       \
      async_copy16(_g + (8 << 10), _l + 512);                                     \
    }

  #define SRC_A(s, H) (xs + (((size_t)((s) >> 4) * N_TOK + t0 + (H) * 128) << 10) + (((s) & 15) << 6))
  #define SRC_B(s, H) (wt + (((size_t)((s) >> 4) * HOUT + h0 + (H) * 128) << 10) + (((s) & 15) << 6))

  short8 af[4][2], b0f[2][2], b1f[2][2];

  #define LOAD_A(mh)                                                              \
    _Pragma("unroll") for (int m2 = 0; m2 < 4; m2++)                              \
      _Pragma("unroll") for (int ks = 0; ks < 2; ks++)                            \
        af[m2][ks] = *(const short8*)(&ldsA[p][(((mh) * 128 + wm * 64 + m2 * 16 + l15) << 6) + co[ks]]);

  #define LOAD_B(dst, nh)                                                         \
    _Pragma("unroll") for (int n2 = 0; n2 < 2; n2++)                              \
      _Pragma("unroll") for (int ks = 0; ks < 2; ks++)                            \
        dst[n2][ks] = *(const short8*)(&ldsB[p][((wn * 64 + (nh) * 32 + n2 * 16 + l15) << 6) + co[ks]]);

  #define MFMA_Q(mh, nh, B)                                                       \
    __builtin_amdgcn_s_setprio(1);                                                \
    _Pragma("unroll") for (int m2 = 0; m2 < 4; m2++)                              \
      _Pragma("unroll") for (int n2 = 0; n2 < 2; n2++)                            \
        _Pragma("unroll") for (int ks = 0; ks < 2; ks++)                          \
          acc[(mh) * 4 + m2][(nh) * 2 + n2] = __builtin_amdgcn_mfma_f32_16x16x32_bf16( \
              af[m2][ks], B[n2][ks], acc[(mh) * 4 + m2][(nh) * 2 + n2], 0, 0, 0); \
    __builtin_amdgcn_s_setprio(0);

  #define WAIT6 asm volatile("s_waitcnt vmcnt(6)" ::: "memory")
  #define WAIT0 asm volatile("s_waitcnt vmcnt(0)" ::: "memory")

  const int NT = NEXP * 16;   // 128 K-tiles

  // prologue in ledger order: A0(0), B0(0), B1(0), A1(0), A0(1)
  STAGE_HALF(SRC_A(0, 0), &ldsA[0][0]);
  STAGE_HALF(SRC_B(0, 0), &ldsB[0][0]);
  STAGE_HALF(SRC_B(0, 1), &ldsB[0][8192]);
  STAGE_HALF(SRC_A(0, 1), &ldsA[0][8192]);
  STAGE_HALF(SRC_A(1, 0), &ldsA[1][0]);
  WAIT6;                      // completes A0(0), B0(0)
  wave_barrier();

  for (int u = 0; u < NT; ++u){
    const int p = u & 1;
    const int s1 = u + 1, s2 = u + 2;
    const bool deep = (u < NT - 2);
    // ---- P1: read A0 + B0(persistent); stage B0(s1); Q(0,0) ----
    LOAD_A(0); LOAD_B(b0f, 0);
    if (s1 < NT) STAGE_HALF(SRC_B(s1, 0), &ldsB[p ^ 1][0]);
    MFMA_Q(0, 0, b0f);
    if (deep) { WAIT6; } else { WAIT0; }
    wave_barrier();
    // ---- P2: read B1; stage B1(s1); Q(0,1) ----
    LOAD_B(b1f, 1);
    if (s1 < NT) STAGE_HALF(SRC_B(s1, 1), &ldsB[p ^ 1][8192]);
    MFMA_Q(0, 1, b1f);
    if (deep) { WAIT6; } else { WAIT0; }
    wave_barrier();
    // ---- P3: read A1; stage A1(s1); Q(1,1); no vm wait ----
    LOAD_A(1);
    if (s1 < NT) STAGE_HALF(SRC_A(s1, 1), &ldsA[p ^ 1][8192]);
    MFMA_Q(1, 1, b1f);
    wave_barrier();
    // ---- P4: reuse b0f (no read); stage A0(s2) into buf[p]; Q(1,0) ----
    if (s2 < NT) STAGE_HALF(SRC_A(s2, 0), &ldsA[p][0]);
    MFMA_Q(1, 0, b0f);
    if (deep) { WAIT6; } else { WAIT0; }
    wave_barrier();
  }

  // epilogue: C frag layout col=l15, row=lgp*4+rr
  float bv[8][4];
  #pragma unroll
  for (int e = 0; e < 8; e++)
    #pragma unroll
    for (int n = 0; n < 4; n++)
      bv[e][n] = bias[e * HOUT + h0 + wn * 64 + n * 16 + l15];
  #pragma unroll
  for (int m = 0; m < 8; m++){
    const int mh = m >> 2, m2 = m & 3;
    #pragma unroll
    for (int rr = 0; rr < 4; rr++){
      const int tok = t0 + mh * 128 + wm * 64 + m2 * 16 + lgp * 4 + rr;
      const float4* gp = (const float4*)(gates + tok * NEXP);
      float4 g0 = gp[0], g1 = gp[1];
      #pragma unroll
      for (int n = 0; n < 4; n++){
        float gb = g0.x * bv[0][n] + g0.y * bv[1][n] + g0.z * bv[2][n] + g0.w * bv[3][n]
                 + g1.x * bv[4][n] + g1.y * bv[5][n] + g1.z * bv[6][n] + g1.w * bv[7][n];
        out[(size_t)tok * HOUT + h0 + wn * 64 + n * 16 + l15] = acc[m][n][rr] + gb;
      }
    }
  }
  #undef STAGE_HALF
  #undef SRC_A
  #undef SRC_B
  #undef LOAD_A
  #undef LOAD_B
  #undef MFMA_Q
  #undef WAIT6
  #undef WAIT0
}

// ---------------- fallback: round-3 fused GEMM (gate folded at stage) ----------------
__global__ __launch_bounds__(256, 2) void moe_gemm_kernel(
    const u16* __restrict__ xb, const u16* __restrict__ wt,
    const float* __restrict__ gates, const float* __restrict__ bias,
    float* __restrict__ out){
  __shared__ u16 lds_a[2][128 * 64];
  __shared__ u16 lds_b[2][128 * 64];
  const int t    = threadIdx.x;
  const int lane = t & 63;
  const int wave = t >> 6;
  const int wm = wave >> 1, wn = wave & 1;
  const int wg = (blockIdx.x & 7) * 128 + (blockIdx.x >> 3);
  const int t0 = (wg & 31) * 128, h0 = (wg >> 5) * 128;
  const int l15 = lane & 15, lgp = lane >> 4;

  const f32x4 z4 = {0.f, 0.f, 0.f, 0.f};
  f32x4 acc[4][4];
  #pragma unroll
  for (int mi = 0; mi < 4; mi++)
    #pragma unroll
    for (int nj = 0; nj < 4; nj++) acc[mi][nj] = z4;

  int ldsoff[4], srcoff[4], rowid[4];
  #pragma unroll
  for (int j = 0; j < 4; j++){
    int slot = j * 256 + t;
    int r = slot >> 3, c = slot & 7;
    ldsoff[j] = r * 64 + ((c ^ (r & 7)) * 8);
    srcoff[j] = r * DIM + c * 8;
    rowid[j]  = r;
  }
  const u16* aB = xb + (size_t)t0 * DIM;

  float gj[4];
  #pragma unroll
  for (int j = 0; j < 4; j++) gj[j] = gates[(t0 + rowid[j]) * NEXP + 0];

  uint4 ra[4], rb[4];
  {
    const u16* bB = wt + (size_t)h0 * DIM;
    #pragma unroll
    for (int j = 0; j < 4; j++){
      ra[j] = *(const uint4*)(aB + srcoff[j]);
      rb[j] = *(const uint4*)(bB + srcoff[j]);
    }
  }
  #pragma unroll
  for (int j = 0; j < 4; j++){
    uint4 sa;
    sa.x = scale2bf(ra[j].x, gj[j]); sa.y = scale2bf(ra[j].y, gj[j]);
    sa.z = scale2bf(ra[j].z, gj[j]); sa.w = scale2bf(ra[j].w, gj[j]);
    *(uint4*)(&lds_a[0][ldsoff[j]]) = sa;
    *(uint4*)(&lds_b[0][ldsoff[j]]) = rb[j];
  }
  __syncthreads();

  const int NT = NEXP * 16;
  int cur = 0;
  for (int tt = 0; tt < NT; ++tt){
    const int nt_ = tt + 1;
    const bool havenext = nt_ < NT;
    if (havenext){
      const int e = nt_ >> 4, s = nt_ & 15;
      const int k0 = s * 64;
      const u16* aP = aB + k0;
      const u16* bB = wt + ((size_t)e * HOUT + h0) * DIM + k0;
      #pragma unroll
      for (int j = 0; j < 4; j++){
        ra[j] = *(const uint4*)(aP + srcoff[j]);
        rb[j] = *(const uint4*)(bB + srcoff[j]);
      }
      if ((nt_ & 15) == 0){
        #pragma unroll
        for (int j = 0; j < 4; j++) gj[j] = gates[(t0 + rowid[j]) * NEXP + e];
      }
    }
    #pragma unroll
    for (int ks = 0; ks < 2; ks++){
      short8 af[4], bf[4];
      #pragma unroll
      for (int mi = 0; mi < 4; mi++){
        int r = wm * 64 + mi * 16 + l15;
        int ch = (ks * 4 + lgp) ^ (r & 7);
        af[mi] = *(const short8*)(&lds_a[cur][r * 64 + ch * 8]);
      }
      #pragma unroll
      for (int nj = 0; nj < 4; nj++){
        int r = wn * 64 + nj * 16 + l15;
        int ch = (ks * 4 + lgp) ^ (r & 7);
        bf[nj] = *(const short8*)(&lds_b[cur][r * 64 + ch * 8]);
      }
      #pragma unroll
      for (int mi = 0; mi < 4; mi++)
        #pragma unroll
        for (int nj = 0; nj < 4; nj++)
          acc[mi][nj] = __builtin_amdgcn_mfma_f32_16x16x32_bf16(
              af[mi], bf[nj], acc[mi][nj], 0, 0, 0);
    }
    if (havenext){
      #pragma unroll
      for (int j = 0; j < 4; j++){
        uint4 sa;
        sa.x = scale2bf(ra[j].x, gj[j]); sa.y = scale2bf(ra[j].y, gj[j]);
        sa.z = scale2bf(ra[j].z, gj[j]); sa.w = scale2bf(ra[j].w, gj[j]);
        *(uint4*)(&lds_a[cur ^ 1][ldsoff[j]]) = sa;
        *(uint4*)(&lds_b[cur ^ 1][ldsoff[j]]) = rb[j];
      }
    }
    __syncthreads();
    cur ^= 1;
  }

  float bv[8][4];
  #pragma unroll
  for (int e = 0; e < 8; e++)
    #pragma unroll
    for (int nj = 0; nj < 4; nj++)
      bv[e][nj] = bias[e * HOUT + h0 + wn * 64 + nj * 16 + l15];
  #pragma unroll
  for (int mi = 0; mi < 4; mi++)
    #pragma unroll
    for (int r = 0; r < 4; r++){
      const int tok = t0 + wm * 64 + mi * 16 + lgp * 4 + r;
      const float4* gp = (const float4*)(gates + tok * NEXP);
      float4 g0 = gp[0], g1 = gp[1];
      #pragma unroll
      for (int nj = 0; nj < 4; nj++){
        float gb = g0.x * bv[0][nj] + g0.y * bv[1][nj] + g0.z * bv[2][nj] + g0.w * bv[3][nj]
                 + g1.x * bv[4][nj] + g1.y * bv[5][nj] + g1.z * bv[6][nj] + g1.w * bv[7][nj];
        out[(size_t)tok * HOUT + h0 + wn * 64 + nj * 16 + l15] = acc[mi][nj][r] + gb;
      }
    }
}

extern "C" void kernel_launch(void* const* d_in, const int* in_sizes, int n_in,
                              void* d_out, int out_size, void* d_ws, size_t ws_size,
                              hipStream_t stream){
  (void)in_sizes; (void)n_in; (void)out_size;
  const float* x       = (const float*)d_in[0];
  const float* noise   = (const float*)d_in[1];
  const float* w_gate  = (const float*)d_in[2];
  const float* w_noise = (const float*)d_in[3];
  const float* W       = (const float*)d_in[4];
  const float* b       = (const float*)d_in[5];
  float* out = (float*)d_out;

  char* ws = (char*)d_ws;
  const size_t GATES_B = (size_t)N_TOK * NEXP * 4;             // 128 KB
  const size_t XS_B    = (size_t)NEXP * N_TOK * DIM * 2;       // 64 MB (scaled A copies)
  const size_t WT_B    = (size_t)NEXP * HOUT * DIM * 2;        // 64 MB
  const size_t XB_B    = (size_t)N_TOK * DIM * 2;              // 8 MB (fallback)

  if (ws_size >= GATES_B + XS_B + WT_B){
    // ---- primary path: pre-scaled A + 256^2 8-phase GEMM ----
    float* gates = (float*)ws;
    u32*   xs    = (u32*)(ws + GATES_B);
    u16*   wt    = (u16*)(ws + GATES_B + XS_B);
    hipLaunchKernelGGL(gating_kernel, dim3(N_TOK / 4), dim3(256), 0, stream,
                       x, noise, w_gate, w_noise, gates);
    hipLaunchKernelGGL(transpose_w_kernel, dim3(HOUT / 64, DIM / 64, NEXP), dim3(256), 0, stream, W, wt);
    hipLaunchKernelGGL(scale_x_kernel, dim3((N_TOK * DIM / 8) / 256), dim3(256), 0, stream,
                       x, gates, xs);
    hipLaunchKernelGGL(moe_gemm_8ph_kernel, dim3((N_TOK / 256) * (HOUT / 256)), dim3(512), 0, stream,
                       (const u16*)xs, wt, gates, b, out);
  } else if (ws_size >= GATES_B + XB_B + WT_B){
    // ---- fallback: round-3 path ----
    float* gates = (float*)ws;
    u32*   xb    = (u32*)(ws + GATES_B);
    u16*   wt    = (u16*)(ws + GATES_B + XB_B);
    hipLaunchKernelGGL(convert_x_kernel, dim3((N_TOK * DIM) / (256 * 8)), dim3(256), 0, stream, x, xb);
    hipLaunchKernelGGL(transpose_w_kernel, dim3(HOUT / 64, DIM / 64, NEXP), dim3(256), 0, stream, W, wt);
    hipLaunchKernelGGL(gating_kernel, dim3(N_TOK / 4), dim3(256), 0, stream, x, noise, w_gate, w_noise, gates);
    hipLaunchKernelGGL(moe_gemm_kernel, dim3((N_TOK / 128) * (HOUT / 128)), dim3(256), 0, stream,
                       (const u16*)xb, wt, gates, b, out);
  }
}

// Round 14
// 278.256 us; speedup vs baseline: 1.0539x; 1.0295x over previous
//
#include <hip/hip_runtime.h>
#include <hip/hip_bf16.h>
#include <cstdint>

#define N_TOK 4096
#define DIM   1024
#define HOUT  4096
#define NEXP  8

typedef unsigned short u16;
typedef unsigned int   u32;
typedef __attribute__((ext_vector_type(8))) short short8;
typedef __attribute__((ext_vector_type(4))) float f32x4;

// round-to-nearest-even f32 -> bf16, packed pair into u32 (lo, hi)
__device__ __forceinline__ u32 pack2bf(float lo, float hi){
  u32 a = __float_as_uint(lo);
  a = (a + 0x7fffu + ((a >> 16) & 1u)) >> 16;
  u32 b = __float_as_uint(hi);
  b = (b + 0x7fffu + ((b >> 16) & 1u)) & 0xffff0000u;
  return (a & 0xffffu) | b;
}

// scale two packed bf16 by g, repack via HW cvt_pk (RNE)
__device__ __forceinline__ u32 scale2bf(u32 v, float g){
  float lo = __uint_as_float(v << 16) * g;
  float hi = __uint_as_float(v & 0xffff0000u) * g;
  u32 r;
  asm("v_cvt_pk_bf16_f32 %0, %1, %2" : "=v"(r) : "v"(lo), "v"(hi));
  return r;
}

// async global->LDS, 16B per lane. LDS dest = wave-uniform base + lane*16.
__device__ __forceinline__ void async_copy16(const u16* g, u16* l){
  __builtin_amdgcn_global_load_lds(
      (const __attribute__((address_space(1))) void*)g,
      (__attribute__((address_space(3))) void*)l, 16, 0, 0);
}

__device__ __forceinline__ void wave_barrier(){
  asm volatile("" ::: "memory");
  __builtin_amdgcn_s_barrier();
  asm volatile("" ::: "memory");
}

// ---------------- X f32 -> bf16 (fallback path only) ----------------
__global__ __launch_bounds__(256) void convert_x_kernel(const float* __restrict__ x,
                                                        u32* __restrict__ xb){
  int i = (blockIdx.x * 256 + threadIdx.x) * 8;
  const float4* p = (const float4*)(x + i);
  float4 a = p[0], b = p[1];
  uint4 v;
  v.x = pack2bf(a.x, a.y);
  v.y = pack2bf(a.z, a.w);
  v.z = pack2bf(b.x, b.y);
  v.w = pack2bf(b.z, b.w);
  *(uint4*)(xb + (i >> 1)) = v;
}

// ---- scale_x (fallback path): xs[e][n][d] = bf16(g[n][e] * x[n][d]) ----
__global__ __launch_bounds__(256) void scale_x_kernel(const float* __restrict__ x,
                                                      const float* __restrict__ gates,
                                                      u32* __restrict__ xs){
  int i = blockIdx.x * 256 + threadIdx.x;     // one thread -> 8 elems x 8 experts
  int d8 = (i & 127) * 8;
  int n  = i >> 7;
  const float4* p = (const float4*)(x + (size_t)n * DIM + d8);
  float4 a = p[0], b = p[1];
  const float4* gp = (const float4*)(gates + n * NEXP);
  float4 g0 = gp[0], g1 = gp[1];
  float gv[8] = {g0.x, g0.y, g0.z, g0.w, g1.x, g1.y, g1.z, g1.w};
  #pragma unroll
  for (int e = 0; e < 8; e++){
    float g = gv[e];
    uint4 v;
    v.x = pack2bf(a.x * g, a.y * g);
    v.y = pack2bf(a.z * g, a.w * g);
    v.z = pack2bf(b.x * g, b.y * g);
    v.w = pack2bf(b.z * g, b.w * g);
    *(uint4*)(xs + (((size_t)e * N_TOK + n) * DIM + d8) / 2) = v;
  }
}

// ---------------- W [E][D][H] f32 -> WT [E][H][D] bf16 ----------------
__global__ __launch_bounds__(256) void transpose_w_kernel(const float* __restrict__ W,
                                                          u16* __restrict__ WT){
  __shared__ float tile[64 * 68];
  const int t = threadIdx.x;
  const int h0 = blockIdx.x * 64, d0 = blockIdx.y * 64, e = blockIdx.z;
  const float* Wp = W + (size_t)e * DIM * HOUT + (size_t)d0 * HOUT + h0;
  #pragma unroll
  for (int p = 0; p < 4; p++){
    int d = p * 16 + (t >> 4);
    int c = (t & 15) * 4;
    float4 v = *(const float4*)(Wp + (size_t)d * HOUT + c);
    *(float4*)&tile[d * 68 + c] = v;
  }
  __syncthreads();
  const int h = t >> 2, dc = (t & 3) * 16;
  u32 o[8];
  #pragma unroll
  for (int j = 0; j < 8; j++){
    float v0 = tile[(dc + 2 * j)     * 68 + h];
    float v1 = tile[(dc + 2 * j + 1) * 68 + h];
    o[j] = pack2bf(v0, v1);
  }
  u16* dst = WT + (size_t)e * HOUT * DIM + (size_t)(h0 + h) * DIM + d0 + dc;
  uint4 v0; v0.x = o[0]; v0.y = o[1]; v0.z = o[2]; v0.w = o[3];
  uint4 v1; v1.x = o[4]; v1.y = o[5]; v1.z = o[6]; v1.w = o[7];
  *(uint4*)(dst)     = v0;
  *(uint4*)(dst + 8) = v1;
}

// ======== fused gating + scale: one block = 4 tokens ========
// Phase A (wave w = token slot w): noisy top-4 gating; x row cached in LDS.
// Phase B: xs[e][n][d] = bf16(g * x) from LDS. Conflict-free: rep = (e,tok)
// row, thread t reads consecutive 16B f32 chunks (stride-1), stores uint2.
__global__ __launch_bounds__(256) void gate_scale_kernel(
    const float* __restrict__ x, const float* __restrict__ noise,
    const float* __restrict__ w_gate, const float* __restrict__ w_noise,
    float* __restrict__ gates, u32* __restrict__ xs){
  __shared__ float xsh[4][DIM];
  __shared__ float gsh[4][8];
  const int lane = threadIdx.x & 63;
  const int w = threadIdx.x >> 6;
  const int n = blockIdx.x * 4 + w;
  float ag[8], an[8];
  #pragma unroll
  for (int e = 0; e < 8; e++){ ag[e] = 0.f; an[e] = 0.f; }
  const float* xr = x + (size_t)n * DIM;
  for (int i = 0; i < DIM / 64; i++){
    int d = i * 64 + lane;
    float xv = xr[d];
    xsh[w][d] = xv;
    float4 g0 = *(const float4*)(w_gate  + d * 8);
    float4 g1 = *(const float4*)(w_gate  + d * 8 + 4);
    float4 s0 = *(const float4*)(w_noise + d * 8);
    float4 s1 = *(const float4*)(w_noise + d * 8 + 4);
    ag[0] += xv * g0.x; ag[1] += xv * g0.y; ag[2] += xv * g0.z; ag[3] += xv * g0.w;
    ag[4] += xv * g1.x; ag[5] += xv * g1.y; ag[6] += xv * g1.z; ag[7] += xv * g1.w;
    an[0] += xv * s0.x; an[1] += xv * s0.y; an[2] += xv * s0.z; an[3] += xv * s0.w;
    an[4] += xv * s1.x; an[5] += xv * s1.y; an[6] += xv * s1.z; an[7] += xv * s1.w;
  }
  #pragma unroll
  for (int off = 32; off > 0; off >>= 1){
    #pragma unroll
    for (int e = 0; e < 8; e++){
      ag[e] += __shfl_xor(ag[e], off);
      an[e] += __shfl_xor(an[e], off);
    }
  }
  if (lane == 0){
    float lg[8];
    #pragma unroll
    for (int e = 0; e < 8; e++){
      float z = an[e];
      float sp = fmaxf(z, 0.f) + log1pf(expf(-fabsf(z)));   // stable softplus
      lg[e] = ag[e] + noise[n * 8 + e] * (sp + 1e-2f);
    }
    bool used[8] = {false,false,false,false,false,false,false,false};
    float tv[4]; int ti[4];
    #pragma unroll
    for (int k = 0; k < 4; k++){
      float best = -1e30f; int bi = 0;
      #pragma unroll
      for (int e = 0; e < 8; e++)
        if (!used[e] && lg[e] > best){ best = lg[e]; bi = e; }
      used[bi] = true; tv[k] = best; ti[k] = bi;
    }
    float m = tv[0];
    float wk[4]; float s = 0.f;
    #pragma unroll
    for (int k = 0; k < 4; k++){ wk[k] = expf(tv[k] - m); s += wk[k]; }
    float inv = 1.f / s;
    float res[8] = {0.f,0.f,0.f,0.f,0.f,0.f,0.f,0.f};
    #pragma unroll
    for (int k = 0; k < 4; k++) res[ti[k]] = wk[k] * inv;
    #pragma unroll
    for (int e = 0; e < 8; e++) gsh[w][e] = res[e];
    float4* gp = (float4*)(gates + n * 8);
    float4 r0; r0.x = res[0]; r0.y = res[1]; r0.z = res[2]; r0.w = res[3];
    float4 r1; r1.x = res[4]; r1.y = res[5]; r1.z = res[6]; r1.w = res[7];
    gp[0] = r0; gp[1] = r1;
  }
  __syncthreads();
  // Phase B: 32 reps, rep = e*4 + tok; thread t handles 16B chunk t (4 f32)
  const int t = threadIdx.x;
  #pragma unroll
  for (int rep = 0; rep < 32; rep++){
    const int e = rep >> 2, tok = rep & 3;
    const float g = gsh[tok][e];
    float4 a = *(const float4*)(&xsh[tok][t * 4]);
    uint2 v;
    v.x = pack2bf(a.x * g, a.y * g);
    v.y = pack2bf(a.z * g, a.w * g);
    *(uint2*)(xs + (((size_t)e * N_TOK + blockIdx.x * 4 + tok) * DIM + t * 4) / 2) = v;
  }
}

// ---------------- gating only (fallback path) ----------------
__global__ __launch_bounds__(256) void gating_kernel(const float* __restrict__ x,
                                                     const float* __restrict__ noise,
                                                     const float* __restrict__ w_gate,
                                                     const float* __restrict__ w_noise,
                                                     float* __restrict__ gates){
  const int lane = threadIdx.x & 63;
  const int n = blockIdx.x * 4 + (threadIdx.x >> 6);
  float ag[8], an[8];
  #pragma unroll
  for (int e = 0; e < 8; e++){ ag[e] = 0.f; an[e] = 0.f; }
  const float* xr = x + (size_t)n * DIM;
  for (int i = 0; i < DIM / 64; i++){
    int d = i * 64 + lane;
    float xv = xr[d];
    float4 g0 = *(const float4*)(w_gate  + d * 8);
    float4 g1 = *(const float4*)(w_gate  + d * 8 + 4);
    float4 s0 = *(const float4*)(w_noise + d * 8);
    float4 s1 = *(const float4*)(w_noise + d * 8 + 4);
    ag[0] += xv * g0.x; ag[1] += xv * g0.y; ag[2] += xv * g0.z; ag[3] += xv * g0.w;
    ag[4] += xv * g1.x; ag[5] += xv * g1.y; ag[6] += xv * g1.z; ag[7] += xv * g1.w;
    an[0] += xv * s0.x; an[1] += xv * s0.y; an[2] += xv * s0.z; an[3] += xv * s0.w;
    an[4] += xv * s1.x; an[5] += xv * s1.y; an[6] += xv * s1.z; an[7] += xv * s1.w;
  }
  #pragma unroll
  for (int off = 32; off > 0; off >>= 1){
    #pragma unroll
    for (int e = 0; e < 8; e++){
      ag[e] += __shfl_xor(ag[e], off);
      an[e] += __shfl_xor(an[e], off);
    }
  }
  if (lane == 0){
    float lg[8];
    #pragma unroll
    for (int e = 0; e < 8; e++){
      float z = an[e];
      float sp = fmaxf(z, 0.f) + log1pf(expf(-fabsf(z)));
      lg[e] = ag[e] + noise[n * 8 + e] * (sp + 1e-2f);
    }
    bool used[8] = {false,false,false,false,false,false,false,false};
    float tv[4]; int ti[4];
    #pragma unroll
    for (int k = 0; k < 4; k++){
      float best = -1e30f; int bi = 0;
      #pragma unroll
      for (int e = 0; e < 8; e++)
        if (!used[e] && lg[e] > best){ best = lg[e]; bi = e; }
      used[bi] = true; tv[k] = best; ti[k] = bi;
    }
    float m = tv[0];
    float w[4]; float s = 0.f;
    #pragma unroll
    for (int k = 0; k < 4; k++){ w[k] = expf(tv[k] - m); s += w[k]; }
    float inv = 1.f / s;
    float res[8] = {0.f,0.f,0.f,0.f,0.f,0.f,0.f,0.f};
    #pragma unroll
    for (int k = 0; k < 4; k++) res[ti[k]] = w[k] * inv;
    float4* gp = (float4*)(gates + n * 8);
    float4 r0; r0.x = res[0]; r0.y = res[1]; r0.z = res[2]; r0.w = res[3];
    float4 r1; r1.x = res[4]; r1.y = res[5]; r1.z = res[6]; r1.w = res[7];
    gp[0] = r0; gp[1] = r1;
  }
}

// ============ 256x256 8-phase GEMM over pre-scaled A (xs) ============
// Round-5 proven schedule + B0-persistent registers (round-13, verified).
// Counted-vmcnt ledger (2 loads per half-tile), steady state:
//   end P1: vmcnt(6) completes B1(u)   [read P2 after barrier]
//   end P2: vmcnt(6) completes A1(u)   [read P3 after barrier]
//   end P3: no wait
//   end P4: vmcnt(6) completes A0(u+1), B0(u+1)  [read P1(u+1) after barrier]
__global__ __launch_bounds__(512, 1) void moe_gemm_8ph_kernel(
    const u16* __restrict__ xs, const u16* __restrict__ wt,
    const float* __restrict__ gates, const float* __restrict__ bias,
    float* __restrict__ out){
  __shared__ u16 ldsA[2][16384];   // [buf][256 rows x 64 k] 32 KB each
  __shared__ u16 ldsB[2][16384];
  const int t    = threadIdx.x;
  const int lane = t & 63;
  const int wave = t >> 6;
  const int wm = wave >> 2;              // 0..1
  const int wn = wave & 3;               // 0..3
  const int l15 = lane & 15, lgp = lane >> 4;
  const int l7 = lane & 7, l8 = lane >> 3;

  // bijective XCD swizzle: 256 wgs = 8 XCDs x 32
  const int wg = (blockIdx.x & 7) * 32 + (blockIdx.x >> 3);
  const int t0 = (wg & 15) * 256, h0 = (wg >> 4) * 256;

  const f32x4 z4 = {0.f, 0.f, 0.f, 0.f};
  f32x4 acc[8][4];
  #pragma unroll
  for (int m = 0; m < 8; m++)
    #pragma unroll
    for (int n = 0; n < 4; n++) acc[m][n] = z4;

  // swizzled read chunk offsets (u16 units): chunk = (ks*4+lgp) ^ (l15&7)
  const int co[2] = { ((0 + lgp) ^ (l15 & 7)) << 3, ((4 + lgp) ^ (l15 & 7)) << 3 };

  // staging: lane l covers row w*16 + i*8 + (l>>3); physical chunk l&7 holds
  // logical (l&7)^(l>>3) (pre-swizzled global source, linear LDS dest).
  const int srcChunkOff = ((l7 ^ l8) << 3);            // u16
  const int srcRowOff   = (l8) << 10;                  // row (l>>3) * 1024 elems
  const int ldsLaneOff  = lane << 3;                   // lane * 16B

  #define STAGE_HALF(srcbase, ldshalf)                                            \
    {                                                                             \
      const u16* _g = (srcbase) + ((size_t)(wave * 16) << 10) + srcRowOff + srcChunkOff; \
      u16* _l = (ldshalf) + (wave << 10) + ldsLaneOff;                            \
      async_copy16(_g, _l);                                                       \
      async_copy16(_g + (8 << 10), _l + 512);                                     \
    }

  #define SRC_A(s, H) (xs + (((size_t)((s) >> 4) * N_TOK + t0 + (H) * 128) << 10) + (((s) & 15) << 6))
  #define SRC_B(s, H) (wt + (((size_t)((s) >> 4) * HOUT + h0 + (H) * 128) << 10) + (((s) & 15) << 6))

  short8 af[4][2], b0f[2][2], b1f[2][2];

  #define LOAD_A(mh)                                                              \
    _Pragma("unroll") for (int m2 = 0; m2 < 4; m2++)                              \
      _Pragma("unroll") for (int ks = 0; ks < 2; ks++)                            \
        af[m2][ks] = *(const short8*)(&ldsA[p][(((mh) * 128 + wm * 64 + m2 * 16 + l15) << 6) + co[ks]]);

  #define LOAD_B(dst, nh)                                                         \
    _Pragma("unroll") for (int n2 = 0; n2 < 2; n2++)                              \
      _Pragma("unroll") for (int ks = 0; ks < 2; ks++)                            \
        dst[n2][ks] = *(const short8*)(&ldsB[p][((wn * 64 + (nh) * 32 + n2 * 16 + l15) << 6) + co[ks]]);

  #define MFMA_Q(mh, nh, B)                                                       \
    __builtin_amdgcn_s_setprio(1);                                                \
    _Pragma("unroll") for (int m2 = 0; m2 < 4; m2++)                              \
      _Pragma("unroll") for (int n2 = 0; n2 < 2; n2++)                            \
        _Pragma("unroll") for (int ks = 0; ks < 2; ks++)                          \
          acc[(mh) * 4 + m2][(nh) * 2 + n2] = __builtin_amdgcn_mfma_f32_16x16x32_bf16( \
              af[m2][ks], B[n2][ks], acc[(mh) * 4 + m2][(nh) * 2 + n2], 0, 0, 0); \
    __builtin_amdgcn_s_setprio(0);

  #define WAIT6 asm volatile("s_waitcnt vmcnt(6)" ::: "memory")
  #define WAIT0 asm volatile("s_waitcnt vmcnt(0)" ::: "memory")

  const int NT = NEXP * 16;   // 128 K-tiles

  // prologue in ledger order: A0(0), B0(0), B1(0), A1(0), A0(1)
  STAGE_HALF(SRC_A(0, 0), &ldsA[0][0]);
  STAGE_HALF(SRC_B(0, 0), &ldsB[0][0]);
  STAGE_HALF(SRC_B(0, 1), &ldsB[0][8192]);
  STAGE_HALF(SRC_A(0, 1), &ldsA[0][8192]);
  STAGE_HALF(SRC_A(1, 0), &ldsA[1][0]);
  WAIT6;                      // completes A0(0), B0(0)
  wave_barrier();

  for (int u = 0; u < NT; ++u){
    const int p = u & 1;
    const int s1 = u + 1, s2 = u + 2;
    const bool deep = (u < NT - 2);
    // ---- P1: read A0 + B0(persistent); stage B0(s1); Q(0,0) ----
    LOAD_A(0); LOAD_B(b0f, 0);
    if (s1 < NT) STAGE_HALF(SRC_B(s1, 0), &ldsB[p ^ 1][0]);
    MFMA_Q(0, 0, b0f);
    if (deep) { WAIT6; } else { WAIT0; }
    wave_barrier();
    // ---- P2: read B1; stage B1(s1); Q(0,1) ----
    LOAD_B(b1f, 1);
    if (s1 < NT) STAGE_HALF(SRC_B(s1, 1), &ldsB[p ^ 1][8192]);
    MFMA_Q(0, 1, b1f);
    if (deep) { WAIT6; } else { WAIT0; }
    wave_barrier();
    // ---- P3: read A1; stage A1(s1); Q(1,1); no vm wait ----
    LOAD_A(1);
    if (s1 < NT) STAGE_HALF(SRC_A(s1, 1), &ldsA[p ^ 1][8192]);
    MFMA_Q(1, 1, b1f);
    wave_barrier();
    // ---- P4: reuse b0f (no read); stage A0(s2) into buf[p]; Q(1,0) ----
    if (s2 < NT) STAGE_HALF(SRC_A(s2, 0), &ldsA[p][0]);
    MFMA_Q(1, 0, b0f);
    if (deep) { WAIT6; } else { WAIT0; }
    wave_barrier();
  }

  // epilogue: C frag layout col=l15, row=lgp*4+rr
  float bv[8][4];
  #pragma unroll
  for (int e = 0; e < 8; e++)
    #pragma unroll
    for (int n = 0; n < 4; n++)
      bv[e][n] = bias[e * HOUT + h0 + wn * 64 + n * 16 + l15];
  #pragma unroll
  for (int m = 0; m < 8; m++){
    const int mh = m >> 2, m2 = m & 3;
    #pragma unroll
    for (int rr = 0; rr < 4; rr++){
      const int tok = t0 + mh * 128 + wm * 64 + m2 * 16 + lgp * 4 + rr;
      const float4* gp = (const float4*)(gates + tok * NEXP);
      float4 g0 = gp[0], g1 = gp[1];
      #pragma unroll
      for (int n = 0; n < 4; n++){
        float gb = g0.x * bv[0][n] + g0.y * bv[1][n] + g0.z * bv[2][n] + g0.w * bv[3][n]
                 + g1.x * bv[4][n] + g1.y * bv[5][n] + g1.z * bv[6][n] + g1.w * bv[7][n];
        out[(size_t)tok * HOUT + h0 + wn * 64 + n * 16 + l15] = acc[m][n][rr] + gb;
      }
    }
  }
  #undef STAGE_HALF
  #undef SRC_A
  #undef SRC_B
  #undef LOAD_A
  #undef LOAD_B
  #undef MFMA_Q
  #undef WAIT6
  #undef WAIT0
}

// ---------------- fallback: round-3 fused GEMM (gate folded at stage) ----------------
__global__ __launch_bounds__(256, 2) void moe_gemm_kernel(
    const u16* __restrict__ xb, const u16* __restrict__ wt,
    const float* __restrict__ gates, const float* __restrict__ bias,
    float* __restrict__ out){
  __shared__ u16 lds_a[2][128 * 64];
  __shared__ u16 lds_b[2][128 * 64];
  const int t    = threadIdx.x;
  const int lane = t & 63;
  const int wave = t >> 6;
  const int wm = wave >> 1, wn = wave & 1;
  const int wg = (blockIdx.x & 7) * 128 + (blockIdx.x >> 3);
  const int t0 = (wg & 31) * 128, h0 = (wg >> 5) * 128;
  const int l15 = lane & 15, lgp = lane >> 4;

  const f32x4 z4 = {0.f, 0.f, 0.f, 0.f};
  f32x4 acc[4][4];
  #pragma unroll
  for (int mi = 0; mi < 4; mi++)
    #pragma unroll
    for (int nj = 0; nj < 4; nj++) acc[mi][nj] = z4;

  int ldsoff[4], srcoff[4], rowid[4];
  #pragma unroll
  for (int j = 0; j < 4; j++){
    int slot = j * 256 + t;
    int r = slot >> 3, c = slot & 7;
    ldsoff[j] = r * 64 + ((c ^ (r & 7)) * 8);
    srcoff[j] = r * DIM + c * 8;
    rowid[j]  = r;
  }
  const u16* aB = xb + (size_t)t0 * DIM;

  float gj[4];
  #pragma unroll
  for (int j = 0; j < 4; j++) gj[j] = gates[(t0 + rowid[j]) * NEXP + 0];

  uint4 ra[4], rb[4];
  {
    const u16* bB = wt + (size_t)h0 * DIM;
    #pragma unroll
    for (int j = 0; j < 4; j++){
      ra[j] = *(const uint4*)(aB + srcoff[j]);
      rb[j] = *(const uint4*)(bB + srcoff[j]);
    }
  }
  #pragma unroll
  for (int j = 0; j < 4; j++){
    uint4 sa;
    sa.x = scale2bf(ra[j].x, gj[j]); sa.y = scale2bf(ra[j].y, gj[j]);
    sa.z = scale2bf(ra[j].z, gj[j]); sa.w = scale2bf(ra[j].w, gj[j]);
    *(uint4*)(&lds_a[0][ldsoff[j]]) = sa;
    *(uint4*)(&lds_b[0][ldsoff[j]]) = rb[j];
  }
  __syncthreads();

  const int NT = NEXP * 16;
  int cur = 0;
  for (int tt = 0; tt < NT; ++tt){
    const int nt_ = tt + 1;
    const bool havenext = nt_ < NT;
    if (havenext){
      const int e = nt_ >> 4, s = nt_ & 15;
      const int k0 = s * 64;
      const u16* aP = aB + k0;
      const u16* bB = wt + ((size_t)e * HOUT + h0) * DIM + k0;
      #pragma unroll
      for (int j = 0; j < 4; j++){
        ra[j] = *(const uint4*)(aP + srcoff[j]);
        rb[j] = *(const uint4*)(bB + srcoff[j]);
      }
      if ((nt_ & 15) == 0){
        #pragma unroll
        for (int j = 0; j < 4; j++) gj[j] = gates[(t0 + rowid[j]) * NEXP + e];
      }
    }
    #pragma unroll
    for (int ks = 0; ks < 2; ks++){
      short8 af[4], bf[4];
      #pragma unroll
      for (int mi = 0; mi < 4; mi++){
        int r = wm * 64 + mi * 16 + l15;
        int ch = (ks * 4 + lgp) ^ (r & 7);
        af[mi] = *(const short8*)(&lds_a[cur][r * 64 + ch * 8]);
      }
      #pragma unroll
      for (int nj = 0; nj < 4; nj++){
        int r = wn * 64 + nj * 16 + l15;
        int ch = (ks * 4 + lgp) ^ (r & 7);
        bf[nj] = *(const short8*)(&lds_b[cur][r * 64 + ch * 8]);
      }
      #pragma unroll
      for (int mi = 0; mi < 4; mi++)
        #pragma unroll
        for (int nj = 0; nj < 4; nj++)
          acc[mi][nj] = __builtin_amdgcn_mfma_f32_16x16x32_bf16(
              af[mi], bf[nj], acc[mi][nj], 0, 0, 0);
    }
    if (havenext){
      #pragma unroll
      for (int j = 0; j < 4; j++){
        uint4 sa;
        sa.x = scale2bf(ra[j].x, gj[j]); sa.y = scale2bf(ra[j].y, gj[j]);
        sa.z = scale2bf(ra[j].z, gj[j]); sa.w = scale2bf(ra[j].w, gj[j]);
        *(uint4*)(&lds_a[cur ^ 1][ldsoff[j]]) = sa;
        *(uint4*)(&lds_b[cur ^ 1][ldsoff[j]]) = rb[j];
      }
    }
    __syncthreads();
    cur ^= 1;
  }

  float bv[8][4];
  #pragma unroll
  for (int e = 0; e < 8; e++)
    #pragma unroll
    for (int nj = 0; nj < 4; nj++)
      bv[e][nj] = bias[e * HOUT + h0 + wn * 64 + nj * 16 + l15];
  #pragma unroll
  for (int mi = 0; mi < 4; mi++)
    #pragma unroll
    for (int r = 0; r < 4; r++){
      const int tok = t0 + wm * 64 + mi * 16 + lgp * 4 + r;
      const float4* gp = (const float4*)(gates + tok * NEXP);
      float4 g0 = gp[0], g1 = gp[1];
      #pragma unroll
      for (int nj = 0; nj < 4; nj++){
        float gb = g0.x * bv[0][nj] + g0.y * bv[1][nj] + g0.z * bv[2][nj] + g0.w * bv[3][nj]
                 + g1.x * bv[4][nj] + g1.y * bv[5][nj] + g1.z * bv[6][nj] + g1.w * bv[7][nj];
        out[(size_t)tok * HOUT + h0 + wn * 64 + nj * 16 + l15] = acc[mi][nj][r] + gb;
      }
    }
}

extern "C" void kernel_launch(void* const* d_in, const int* in_sizes, int n_in,
                              void* d_out, int out_size, void* d_ws, size_t ws_size,
                              hipStream_t stream){
  (void)in_sizes; (void)n_in; (void)out_size;
  const float* x       = (const float*)d_in[0];
  const float* noise   = (const float*)d_in[1];
  const float* w_gate  = (const float*)d_in[2];
  const float* w_noise = (const float*)d_in[3];
  const float* W       = (const float*)d_in[4];
  const float* b       = (const float*)d_in[5];
  float* out = (float*)d_out;

  char* ws = (char*)d_ws;
  const size_t GATES_B = (size_t)N_TOK * NEXP * 4;             // 128 KB
  const size_t XS_B    = (size_t)NEXP * N_TOK * DIM * 2;       // 64 MB (scaled A copies)
  const size_t WT_B    = (size_t)NEXP * HOUT * DIM * 2;        // 64 MB
  const size_t XB_B    = (size_t)N_TOK * DIM * 2;              // 8 MB (fallback)

  if (ws_size >= GATES_B + XS_B + WT_B){
    // ---- primary path: fused gating+scale + 256^2 8-phase GEMM ----
    float* gates = (float*)ws;
    u32*   xs    = (u32*)(ws + GATES_B);
    u16*   wt    = (u16*)(ws + GATES_B + XS_B);
    hipLaunchKernelGGL(gate_scale_kernel, dim3(N_TOK / 4), dim3(256), 0, stream,
                       x, noise, w_gate, w_noise, gates, xs);
    hipLaunchKernelGGL(transpose_w_kernel, dim3(HOUT / 64, DIM / 64, NEXP), dim3(256), 0, stream, W, wt);
    hipLaunchKernelGGL(moe_gemm_8ph_kernel, dim3((N_TOK / 256) * (HOUT / 256)), dim3(512), 0, stream,
                       (const u16*)xs, wt, gates, b, out);
  } else if (ws_size >= GATES_B + XB_B + WT_B){
    // ---- fallback: round-3 path ----
    float* gates = (float*)ws;
    u32*   xb    = (u32*)(ws + GATES_B);
    u16*   wt    = (u16*)(ws + GATES_B + XB_B);
    hipLaunchKernelGGL(convert_x_kernel, dim3((N_TOK * DIM) / (256 * 8)), dim3(256), 0, stream, x, xb);
    hipLaunchKernelGGL(transpose_w_kernel, dim3(HOUT / 64, DIM / 64, NEXP), dim3(256), 0, stream, W, wt);
    hipLaunchKernelGGL(gating_kernel, dim3(N_TOK / 4), dim3(256), 0, stream, x, noise, w_gate, w_noise, gates);
    hipLaunchKernelGGL(moe_gemm_kernel, dim3((N_TOK / 128) * (HOUT / 128)), dim3(256), 0, stream,
                       (const u16*)xb, wt, gates, b, out);
  }
}